// Round 1
// 77.170 us; speedup vs baseline: 1.0030x; 1.0030x over previous
//
#include <hip/hip_runtime.h>

// out[0] = event_intensity - non_event_intensity
//
// R6: 8-row tiles. grid = 2048 blocks x 256 (8 blocks/CU x 256 CU, full
// residency). Tile q = blockIdx>>2 owns 8 rows: low group {4q..4q+3} and the
// balanced mirror group {N-4-4q..N-1-4q} (total j-trips ~= N+8 per tile,
// constant). j-range split 4 ways by blockIdx&3 (stride 1024).
//   Each (z2[j], v2[j]) load now feeds FOUR row-evals (R5 halved loads/eval
//   by pairing 2 rows; this halves again: 4 B of load per eval against the
//   64KB z/v set that thrashes 32KB L1). 4 independent acc chains per trip
//   cover L2 latency; loop/address overhead amortized over 4 evals.
//   Row (z,v) loads are block-uniform -> SGPRs, keeping VGPR pressure low.
//   Boundary j<=row lanes masked branchlessly per row (degenerate eval is
//   finite via the a_safe clamp); in-group pairs (j in (r, r0+3]) are covered
//   by the same masked loop, so no corner fixup is needed.
//   Partials -> ws[blockIdx] (no same-address atomics: R3 showed ~36cyc
//   serialized RMW per atomic dominating wall time).
// Kb = sqrt(pi)/2 * e^b hoisted per-thread: exponent becomes fma(u,u,-c)
//   (neg modifier free) - one fewer VALU op per eval.
// finalize_kernel: 1 block, float4-reduce ws -> out[0].
//
// erf approximations (tolerance budget: threshold 2.6e6 on |out|~1.3e8):
//   upper (arg = sqa*tn + u): A&S 7.1.27, |err|<=5e-4 abs, one rcp, no exp.
//   lower (t0==0 uniform fast path, arg = u): |u|<=|dz|<=sqrt(0.5) by
//   Cauchy-Schwarz (survives a_safe clamp) -> 5-term odd Taylor, no trans.

__device__ __forceinline__ float fast_erf_a(float x) {
    // A&S 7.1.26 (rcp + exp), |err| <= 1.5e-7 abs — generic fallback path.
    const float ax = __builtin_fabsf(x);
    const float t  = __builtin_amdgcn_rcpf(fmaf(0.3275911f, ax, 1.0f));
    float p = fmaf(t, 1.061405429f, -1.453152027f);
    p = fmaf(t, p, 1.421413741f);
    p = fmaf(t, p, -0.284496736f);
    p = fmaf(t, p, 0.254829592f);
    const float y = fmaf(-t * p, __expf(-ax * ax), 1.0f);
    return __builtin_copysignf(y, x);
}

__device__ __forceinline__ float fast_erf_b(float x) {
    // A&S 7.1.27: erf(x) ~ 1 - 1/(1+a1x+a2x^2+a3x^3+a4x^4)^4, |err|<=5e-4
    const float ax = __builtin_fabsf(x);
    float p = fmaf(ax, 0.078108f, 0.000972f);
    p = fmaf(ax, p, 0.230389f);
    p = fmaf(ax, p, 0.278393f);
    p = fmaf(ax, p, 1.0f);
    const float w  = __builtin_amdgcn_rcpf(p);
    const float w2 = w * w;
    const float y  = fmaf(-w2, w2, 1.0f);          // 1 - w^4
    return __builtin_copysignf(y, x);
}

__device__ __forceinline__ float erf_small(float x) {
    // odd Taylor of erf, valid |x| <= 0.75, abs err < 2e-5, no trans ops
    const float x2 = x * x;
    float p = fmaf(x2, 0.0052239776f, -0.0268661706f);
    p = fmaf(x2, p, 0.1128379167f);
    p = fmaf(x2, p, -0.3761263890f);
    p = fmaf(x2, p, 1.1283791671f);
    return x * p;
}

template<bool T0Z>
__device__ __forceinline__ float pair_eval(float2 zi, float2 vi,
                                           float2 zj, float2 vj,
                                           float t0, float tn, float Kb) {
    // Kb = sqrt(pi)/2 * e^b (uniform): exponent reduced to u^2 - c
    const float dzx = zi.x - zj.x, dzy = zi.y - zj.y;
    const float dvx = vi.x - vj.x, dvy = vi.y - vj.y;

    const float a  = fmaf(dvx, dvx, dvy * dvy);
    const float du = fmaf(dzx, dvx, dzy * dvy);     // dz.dv = bb/2
    const float c  = fmaf(dzx, dzx, dzy * dzy);

    const float a_safe = fmaxf(a, 1e-10f);
    const float rsq = __builtin_amdgcn_rsqf(a_safe); // 1/sqrt(a_safe)
    const float sqa = a_safe * rsq;                  // sqrt(a_safe)
    const float u   = du * rsq;                      // bb/(2 sqa)

    // exponent = u^2 - c  (<= 0.5; b folded into Kb; safe for __expf)
    const float pref  = Kb * rsq * __expf(fmaf(u, u, -c));
    const float upper = fast_erf_b(fmaf(sqa, tn, u));
    const float lower = T0Z ? erf_small(u)
                            : fast_erf_a(fmaf(sqa, t0, u));
    return pref * (upper - lower);
}

// valid for blockDim <= 1024 (16 waves); result on thread 0
__device__ __forceinline__ float block_reduce_add(float v) {
    __shared__ float smem[16];
    #pragma unroll
    for (int off = 32; off > 0; off >>= 1)
        v += __shfl_down(v, off, 64);
    const int lane = threadIdx.x & 63;
    const int wave = threadIdx.x >> 6;
    if (lane == 0) smem[wave] = v;
    __syncthreads();
    if (threadIdx.x == 0) {
        float s = smem[0];
        const int nw = (int)blockDim.x >> 6;
        for (int w = 1; w < nw; ++w) s += smem[w];
        return s;
    }
    return 0.0f;
}

template<bool T0Z>
__device__ __forceinline__ float quad_tile(int r0, int rvalid_lo, int jofs, int N,
                                           const float2* __restrict__ z2,
                                           const float2* __restrict__ v2,
                                           float t0, float tn, float Kb) {
    // rows r0..r0+3 share every (zj,vj) load; j in (r0, N) stride 1024,
    // per-row mask j>r (and row-validity for generic N).
    const int r1 = r0 + 1, r2i = r0 + 2, r3 = r0 + 3;
    const int hi = N - 1;
    const int c0 = min(max(r0, 0), hi), c1 = min(max(r1, 0), hi);
    const int c2 = min(max(r2i, 0), hi), c3 = min(max(r3, 0), hi);

    // uniform (block-constant) row loads -> SGPRs
    const float2 zr0 = z2[c0], vr0 = v2[c0];
    const float2 zr1 = z2[c1], vr1 = v2[c1];
    const float2 zr2 = z2[c2], vr2 = v2[c2];
    const float2 zr3 = z2[c3], vr3 = v2[c3];

    // mask threshold: invalid rows get +inf threshold so no j passes
    const int BIG = 0x7fffffff;
    const int m0 = (r0  >= rvalid_lo && r0  < N) ? r0  : BIG;
    const int m1 = (r1  >= rvalid_lo && r1  < N) ? r1  : BIG;
    const int m2 = (r2i >= rvalid_lo && r2i < N) ? r2i : BIG;
    const int m3 = (r3  >= rvalid_lo && r3  < N) ? r3  : BIG;

    float s0 = 0.0f, s1 = 0.0f, s2 = 0.0f, s3 = 0.0f;
    for (int j = r0 + 1 + jofs; j < N; j += 1024) {
        const float2 zj = z2[j], vj = v2[j];
        const float e0 = pair_eval<T0Z>(zr0, vr0, zj, vj, t0, tn, Kb);
        const float e1 = pair_eval<T0Z>(zr1, vr1, zj, vj, t0, tn, Kb);
        const float e2 = pair_eval<T0Z>(zr2, vr2, zj, vj, t0, tn, Kb);
        const float e3 = pair_eval<T0Z>(zr3, vr3, zj, vj, t0, tn, Kb);
        s0 += (j > m0) ? e0 : 0.0f;
        s1 += (j > m1) ? e1 : 0.0f;
        s2 += (j > m2) ? e2 : 0.0f;
        s3 += (j > m3) ? e3 : 0.0f;
    }
    return (s0 + s1) + (s2 + s3);
}

__global__ void __launch_bounds__(256)
fused_kernel(const float* __restrict__ data,
             const float* __restrict__ t0p,
             const float* __restrict__ tnp,
             const float* __restrict__ beta,
             const float* __restrict__ z0,
             const float* __restrict__ v0,
             float* __restrict__ ws, int M, int N) {
    const float t0 = t0p[0];
    const float tn = tnp[0];
    const float b  = beta[0];
    const float Kb = 0.88622692545275801f * __expf(b);  // sqrt(pi)/2 * e^b
    const float2* __restrict__ z2 = (const float2*)z0;
    const float2* __restrict__ v2 = (const float2*)v0;

    // ---- pair part first (its loads are the hot path) ----
    const int ntiles  = (N + 7) / 8;
    const int q       = (int)blockIdx.x >> 2;
    const int jofs    = (((int)blockIdx.x & 3) << 8) + (int)threadIdx.x;
    const int rlow    = 4 * q;               // low group rows rlow..rlow+3
    const int rhigh   = N - 4 - rlow;        // mirror group (balanced triangle)
    const int hilimit = 4 * ntiles;          // high rows must be >= this (dedup
                                             // guard; vacuous when N%8==0)
    float acc;
    if (t0 == 0.0f) {  // uniform scalar branch; Taylor lower path needs |u|<=0.71
        float s = quad_tile<true >(rlow,  0,       jofs, N, z2, v2, t0, tn, Kb);
        s      += quad_tile<true >(rhigh, hilimit, jofs, N, z2, v2, t0, tn, Kb);
        acc = -s;
    } else {
        float s = quad_tile<false>(rlow,  0,       jofs, N, z2, v2, t0, tn, Kb);
        s      += quad_tile<false>(rhigh, hilimit, jofs, N, z2, v2, t0, tn, Kb);
        acc = -s;
    }

    // ---- event part: ~32 events per block; cold gathers overlap epilogue ----
    const int chunk = (M + (int)gridDim.x - 1) / (int)gridDim.x;
    const int mbeg  = (int)blockIdx.x * chunk;
    const int mend  = min(mbeg + chunk, M);
    for (int m = mbeg + (int)threadIdx.x; m < mend; m += 256) {
        const float fi = data[3 * m + 0];
        const float fj = data[3 * m + 1];
        const float t  = data[3 * m + 2];
        const int ii = (int)fi;
        const int jj = (int)fj;
        const float2 zi = z2[ii], zj = z2[jj];
        const float2 vi = v2[ii], vj = v2[jj];
        const float dx = (zi.x - zj.x) + (vi.x - vj.x) * t;
        const float dy = (zi.y - zj.y) + (vi.y - vj.y) * t;
        acc += b - (dx * dx + dy * dy);
    }

    const float s = block_reduce_add(acc);
    if (threadIdx.x == 0) ws[blockIdx.x] = s;   // distinct slot: no contention
}

__global__ void __launch_bounds__(1024)
finalize_kernel(const float* __restrict__ ws, float* __restrict__ out,
                int nblocks) {
    const float4* __restrict__ ws4 = (const float4*)ws;
    const int n4 = nblocks >> 2;
    float v = 0.0f;
    for (int k = threadIdx.x; k < n4; k += 1024) {
        const float4 p = ws4[k];
        v += (p.x + p.y) + (p.z + p.w);
    }
    if (threadIdx.x == 0)       // tail (nblocks not multiple of 4)
        for (int k = n4 << 2; k < nblocks; ++k) v += ws[k];
    const float s = block_reduce_add(v);
    if (threadIdx.x == 0) out[0] = s;
}

extern "C" void kernel_launch(void* const* d_in, const int* in_sizes, int n_in,
                              void* d_out, int out_size, void* d_ws, size_t ws_size,
                              hipStream_t stream) {
    const float* data = (const float*)d_in[0];   // (M,3)
    const float* t0   = (const float*)d_in[1];   // scalar
    const float* tn   = (const float*)d_in[2];   // scalar
    const float* beta = (const float*)d_in[3];   // (1,1)
    const float* z0   = (const float*)d_in[4];   // (N,2)
    const float* v0   = (const float*)d_in[5];   // (N,2)
    float* out = (float*)d_out;
    float* ws  = (float*)d_ws;

    const int M = in_sizes[0] / 3;
    const int N = in_sizes[4] / 2;

    const int ntiles = (N + 7) / 8;      // 8 rows (2 balanced quads) per tile
    const int blocks = 4 * ntiles;       // 4 j-chunks per tile -> 2048 for N=4096
    fused_kernel<<<blocks, 256, 0, stream>>>(data, t0, tn, beta, z0, v0, ws, M, N);
    finalize_kernel<<<1, 1024, 0, stream>>>(ws, out, blocks);
}